// Round 2
// baseline (148.592 us; speedup 1.0000x reference)
//
#include <hip/hip_runtime.h>

#define DD   32
#define HH   256
#define BB   4096
#define RR   2      // rows per wave
#define EPSF 1e-12f

// ---------------------------------------------------------------------------
// Degree-sorted layout. deg_h[h] = (h%31)+1. Counts: deg 1..8 -> 9, 9..31 -> 8.
// Sorted position p -> original h:
//   p < 72:  h = (p/9) + 31*(p%9)
//   p >= 72: h = (8+(p-72)/8) + 31*((p-72)%8)
// Group deg==d occupies sorted positions [OFF(d), OFF(d+1)),
//   OFF(d) = (d<=9) ? 9*(d-1) : 8*d   (d>=1; OFF(1)=0, OFF(32)=256)
// For d>=9 the group (8 wide) is 4-aligned: lanes 2d..2d+1, slots 0..3.
// ---------------------------------------------------------------------------
__device__ __forceinline__ int made_pi(int p) {
    return (p < 72) ? (p / 9) + 31 * (p % 9)
                    : (8 + (p - 72) / 8) + 31 * ((p - 72) % 8);
}

// uniform broadcast: lane index must be wave-uniform
__device__ __forceinline__ float rlf(float v, int srclane) {
    return __int_as_float(__builtin_amdgcn_readlane(__float_as_int(v), srclane));
}

// ws float layout:
//   per net n (n=0 mu, n=1 lv), base n*NETF:
//     W0s[32][256] @0 | W1s[256][256] @8192 | b0s[256] @73728 | b1s[256] @73984
//   shared W2i[256][32][2] @ 2*NETF   (W2i[p][dd][n] = Wn2[h(p)][dd])
#define NW0   (DD * HH)                 // 8192
#define NW1   (HH * HH)                 // 65536
#define NETF  (NW0 + NW1 + HH + HH)     // 74240
#define W2IOFF (2 * NETF)
#define NW2I  (HH * 64)                 // 16384
#define WSNEED ((size_t)(W2IOFF + NW2I) * 4)

// ---------------------------------------------------------------------------
// Prep: blocks 0..511 -> W1 rows (LDS-staged permute) + biases;
//       blocks 512..767 -> W2i rows ([p][dd][net] interleave for float2 load);
//       blocks 768..831 -> W0 rows.
// ---------------------------------------------------------------------------
__global__ void made_prep(
    const float* __restrict__ muW0, const float* __restrict__ mub0,
    const float* __restrict__ muW1, const float* __restrict__ mub1,
    const float* __restrict__ muW2,
    const float* __restrict__ lvW0, const float* __restrict__ lvb0,
    const float* __restrict__ lvW1, const float* __restrict__ lvb1,
    const float* __restrict__ lvW2,
    float* __restrict__ ws)
{
    const int t = threadIdx.x;           // 0..63
    const int b = blockIdx.x;
    __shared__ float rowbuf[HH];

    if (b < 512) {
        const int n = b >> 8, p = b & 255;
        const int h = made_pi(p);
        const float* W1 = n ? lvW1 : muW1;
        float* o = ws + (size_t)n * NETF;
        *reinterpret_cast<float4*>(&rowbuf[4 * t]) =
            *reinterpret_cast<const float4*>(W1 + h * HH + 4 * t);
        __syncthreads();
        float4 w;
        w.x = rowbuf[made_pi(4 * t + 0)];
        w.y = rowbuf[made_pi(4 * t + 1)];
        w.z = rowbuf[made_pi(4 * t + 2)];
        w.w = rowbuf[made_pi(4 * t + 3)];
        *reinterpret_cast<float4*>(o + NW0 + p * HH + 4 * t) = w;
        if (t == 0) {
            o[NW0 + NW1 + p]      = (n ? lvb0 : mub0)[h];
            o[NW0 + NW1 + HH + p] = (n ? lvb1 : mub1)[h];
        }
    } else if (b < 768) {
        const int p = b - 512;           // sorted position
        const int h = made_pi(p);
        const int n = t >> 5, dd = t & 31;
        // [p][dd][n] so main can fetch both nets with one float2 load
        ws[W2IOFF + p * 64 + dd * 2 + n] = (n ? lvW2 : muW2)[h * DD + dd];
    } else {
        const int idx = b - 768;         // 0..63
        const int n = idx >> 5, i = idx & 31;
        const float* W0 = n ? lvW0 : muW0;
        float* o = ws + (size_t)n * NETF;
        *reinterpret_cast<float4*>(&rowbuf[4 * t]) =
            *reinterpret_cast<const float4*>(W0 + i * HH + 4 * t);
        __syncthreads();
        float4 w;
        w.x = rowbuf[made_pi(4 * t + 0)];
        w.y = rowbuf[made_pi(4 * t + 1)];
        w.z = rowbuf[made_pi(4 * t + 2)];
        w.w = rowbuf[made_pi(4 * t + 3)];
        *reinterpret_cast<float4*>(o + i * HH + 4 * t) = w;
    }
}

// ---------------------------------------------------------------------------
// R8: LDS-free main loop. All group broadcasts go through v_readlane -> SGPR
// (uniform lane index; compile-time slot index), FMAs consume the SGPR
// directly. Each lane accumulates BOTH nets' outputs (accm/accl; lanes 32-63
// mirror 0-31) so no lane-dependent net select is needed. For d<=8 the
// 9-member unaligned group is handled as a 12-wide 4-aligned window with
// out-of-group source values masked to 0 (exact: 0*w contributions).
// For d>=9 the 8-member group is exactly lanes 2d..2d+1 (4-aligned).
// Numerics are bit-identical to R7 (same contributions, same order).
// ---------------------------------------------------------------------------
template <int W, bool MASK>
__device__ __forceinline__ void made_step(
    const int d, const int off, const int base, const int L0,
    const int c4, const int lane, const int ddl,
    const float* __restrict__ W0m, const float* __restrict__ W0l,
    const float* __restrict__ W1m, const float* __restrict__ W1l,
    const float* __restrict__ W2i,
    float (&h0)[2][4][RR], float (&h1)[2][4][RR],
    float (&accm)[RR], float (&accl)[RR],
    float (&yprev)[RR], float (&lsum)[RR], float (&ysave)[RR],
    const float (&xvr)[RR])
{
    // ================= burst-issue ALL global loads for this step ==========
    const float4 w0m = *reinterpret_cast<const float4*>(W0m + (d - 1) * HH + c4);
    const float4 w0l = *reinterpret_cast<const float4*>(W0l + (d - 1) * HH + c4);
    float4 w1m[W], w1l[W];
    #pragma unroll
    for (int m = 0; m < W; ++m) {
        w1m[m] = *reinterpret_cast<const float4*>(W1m + (base + m) * HH + c4);
        w1l[m] = *reinterpret_cast<const float4*>(W1l + (base + m) * HH + c4);
    }
    float2 w2v[W];
    #pragma unroll
    for (int m = 0; m < W; ++m)
        w2v[m] = *reinterpret_cast<const float2*>(W2i + (base + m) * 64 + 2 * ddl);

    // ================= h0 += y_{d-1} * W0s[d-1,:] (all lanes) ==============
    #pragma unroll
    for (int r = 0; r < RR; ++r) {
        h0[0][0][r] = fmaf(yprev[r], w0m.x, h0[0][0][r]);
        h0[0][1][r] = fmaf(yprev[r], w0m.y, h0[0][1][r]);
        h0[0][2][r] = fmaf(yprev[r], w0m.z, h0[0][2][r]);
        h0[0][3][r] = fmaf(yprev[r], w0m.w, h0[0][3][r]);
        h0[1][0][r] = fmaf(yprev[r], w0l.x, h0[1][0][r]);
        h0[1][1][r] = fmaf(yprev[r], w0l.y, h0[1][1][r]);
        h0[1][2][r] = fmaf(yprev[r], w0l.z, h0[1][2][r]);
        h0[1][3][r] = fmaf(yprev[r], w0l.w, h0[1][3][r]);
    }

    // ---- relu of h0, masked to the degree-d group when the window has pads
    float a0[2][4][RR];
    #pragma unroll
    for (int s = 0; s < 4; ++s) {
        const bool ing = !MASK || ((unsigned)(c4 + s - off) < 9u);
        #pragma unroll
        for (int n = 0; n < 2; ++n)
            #pragma unroll
            for (int r = 0; r < RR; ++r)
                a0[n][s][r] = ing ? fmaxf(h0[n][s][r], 0.f) : 0.f;
    }

    // ================= h1 += av * W1s[window rows] (readlane broadcast) ====
    #pragma unroll
    for (int m = 0; m < W; ++m) {
        const int sl = L0 + (m >> 2);        // uniform source lane
        float avm[RR], avl[RR];
        #pragma unroll
        for (int r = 0; r < RR; ++r) {
            avm[r] = rlf(a0[0][m & 3][r], sl);
            avl[r] = rlf(a0[1][m & 3][r], sl);
        }
        #pragma unroll
        for (int r = 0; r < RR; ++r) {
            h1[0][0][r] = fmaf(avm[r], w1m[m].x, h1[0][0][r]);
            h1[0][1][r] = fmaf(avm[r], w1m[m].y, h1[0][1][r]);
            h1[0][2][r] = fmaf(avm[r], w1m[m].z, h1[0][2][r]);
            h1[0][3][r] = fmaf(avm[r], w1m[m].w, h1[0][3][r]);
            h1[1][0][r] = fmaf(avl[r], w1l[m].x, h1[1][0][r]);
            h1[1][1][r] = fmaf(avl[r], w1l[m].y, h1[1][1][r]);
            h1[1][2][r] = fmaf(avl[r], w1l[m].z, h1[1][2][r]);
            h1[1][3][r] = fmaf(avl[r], w1l[m].w, h1[1][3][r]);
        }
    }

    // ---- relu of h1, masked like a0
    float b1[2][4][RR];
    #pragma unroll
    for (int s = 0; s < 4; ++s) {
        const bool ing = !MASK || ((unsigned)(c4 + s - off) < 9u);
        #pragma unroll
        for (int n = 0; n < 2; ++n)
            #pragma unroll
            for (int r = 0; r < RR; ++r)
                b1[n][s][r] = ing ? fmaxf(h1[n][s][r], 0.f) : 0.f;
    }

    // ================= output accs, both nets per lane =====================
    #pragma unroll
    for (int m = 0; m < W; ++m) {
        const int sl = L0 + (m >> 2);
        #pragma unroll
        for (int r = 0; r < RR; ++r) {
            accm[r] = fmaf(rlf(b1[0][m & 3][r], sl), w2v[m].x, accm[r]);
            accl[r] = fmaf(rlf(b1[1][m & 3][r], sl), w2v[m].y, accl[r]);
        }
    }

    // ================= outputs for dim d ===================================
    #pragma unroll
    for (int r = 0; r < RR; ++r) {
        const float mu  = rlf(accm[r], d);
        const float lv  = rlf(accl[r], d);
        const float ls2 = 0.5f * lv;
        lsum[r] += ls2;
        const float yd = (rlf(xvr[r], d) - mu) / (__expf(ls2) + EPSF);
        yprev[r] = yd;
        if (lane == d) ysave[r] = yd;
    }
}

__global__ __launch_bounds__(256, 2) void made_main(
    const float* __restrict__ ws, const float* __restrict__ x,
    const float* __restrict__ mub2, const float* __restrict__ lvb2,
    float* __restrict__ out)
{
    const int lane = threadIdx.x & 63;
    const int wv   = threadIdx.x >> 6;
    const int row0 = ((blockIdx.x << 2) + wv) * RR;
    const int c4   = lane << 2;          // base sorted position (4 slots/lane)
    const int ddl  = lane & 31;          // output dim of this lane's accs

    const float* W0m = ws;
    const float* W0l = ws + NETF;
    const float* W1m = ws + NW0;
    const float* W1l = ws + NETF + NW0;
    const float* W2i = ws + W2IOFF;

    float h0[2][4][RR], h1[2][4][RR];
    #pragma unroll
    for (int n = 0; n < 2; ++n) {
        const float* bb = ws + (size_t)n * NETF + NW0 + NW1;
        const float4 v0 = *reinterpret_cast<const float4*>(bb + c4);
        const float4 v1 = *reinterpret_cast<const float4*>(bb + HH + c4);
        const float a0i[4] = {v0.x, v0.y, v0.z, v0.w};
        const float a1i[4] = {v1.x, v1.y, v1.z, v1.w};
        #pragma unroll
        for (int s = 0; s < 4; ++s)
            #pragma unroll
            for (int r = 0; r < RR; ++r) { h0[n][s][r] = a0i[s]; h1[n][s][r] = a1i[s]; }
    }

    float accm[RR], accl[RR];
    {
        const float bm = mub2[ddl], bl = lvb2[ddl];
        #pragma unroll
        for (int r = 0; r < RR; ++r) { accm[r] = bm; accl[r] = bl; }
    }

    // x preload: lane l holds x[row_r][l&31]
    float xvr[RR];
    #pragma unroll
    for (int r = 0; r < RR; ++r) xvr[r] = x[(row0 + r) * DD + ddl];

    float yprev[RR], lsum[RR], ysave[RR];
    #pragma unroll
    for (int r = 0; r < RR; ++r) { lsum[r] = 0.f; ysave[r] = 0.f; }

    // ---- step d = 0: no hidden unit finalized yet; acc == b2
    #pragma unroll
    for (int r = 0; r < RR; ++r) {
        const float mu  = rlf(accm[r], 0);
        const float lv  = rlf(accl[r], 0);
        const float ls2 = 0.5f * lv;
        lsum[r] += ls2;
        const float yd = (rlf(xvr[r], 0) - mu) / (__expf(ls2) + EPSF);
        yprev[r] = yd;
        if (lane == 0) ysave[r] = yd;
    }

    // d = 1..8: groups of 9, unaligned -> 12-wide aligned window, masked
    #pragma unroll 1
    for (int d = 1; d <= 8; ++d) {
        const int off  = 9 * (d - 1);
        const int base = off & ~3;
        made_step<12, true>(d, off, base, base >> 2, c4, lane, ddl,
                            W0m, W0l, W1m, W1l, W2i,
                            h0, h1, accm, accl, yprev, lsum, ysave, xvr);
    }
    // d = 9..31: groups of 8, 4-aligned -> exact 8-wide window, no mask
    #pragma unroll 1
    for (int d = 9; d < DD; ++d) {
        const int off = 8 * d;           // == OFF(d) for d>=9
        made_step<8, false>(d, off, off, off >> 2, c4, lane, ddl,
                            W0m, W0l, W1m, W1l, W2i,
                            h0, h1, accm, accl, yprev, lsum, ysave, xvr);
    }

    #pragma unroll
    for (int r = 0; r < RR; ++r) {
        if (lane < DD) out[(row0 + r) * DD + lane] = ysave[r];   // coalesced
        if (lane == 0) out[BB * DD + row0 + r] = lsum[r];
    }
}

// ---------------------------------------------------------------------------
// Fallback (no workspace): R1-style kernel.
// ---------------------------------------------------------------------------
__global__ __launch_bounds__(64, 1) void made_inv_fb(
    const float* __restrict__ x,
    const float* __restrict__ muW0, const float* __restrict__ mub0,
    const float* __restrict__ muW1, const float* __restrict__ mub1,
    const float* __restrict__ muW2, const float* __restrict__ mub2,
    const float* __restrict__ lvW0, const float* __restrict__ lvb0,
    const float* __restrict__ lvW1, const float* __restrict__ lvb1,
    const float* __restrict__ lvW2, const float* __restrict__ lvb2,
    float* __restrict__ out)
{
    const int lane    = threadIdx.x;
    const int rowBase = blockIdx.x * 4;
    const int hb      = lane << 2;
    int deg[4];
    #pragma unroll
    for (int s = 0; s < 4; ++s) deg[s] = ((hb + s) % 31) + 1;
    const float* Wp0[2] = {muW0, lvW0};
    const float* Bp0[2] = {mub0, lvb0};
    const float* Wp1[2] = {muW1, lvW1};
    const float* Bp1[2] = {mub1, lvb1};
    const float* Wp2[2] = {muW2, lvW2};
    float h0pre[2][4][4], h1pre[2][4][4], r1[2][4][4], yprev[4], lsum[4];
    #pragma unroll
    for (int n = 0; n < 2; ++n) {
        const float4 b0v = *reinterpret_cast<const float4*>(Bp0[n] + hb);
        const float4 b1v = *reinterpret_cast<const float4*>(Bp1[n] + hb);
        const float b0a[4] = {b0v.x, b0v.y, b0v.z, b0v.w};
        const float b1a[4] = {b1v.x, b1v.y, b1v.z, b1v.w};
        #pragma unroll
        for (int s = 0; s < 4; ++s)
            #pragma unroll
            for (int r = 0; r < 4; ++r) {
                h0pre[n][s][r] = b0a[s]; h1pre[n][s][r] = b1a[s]; r1[n][s][r] = 0.f;
            }
    }
    #pragma unroll
    for (int r = 0; r < 4; ++r) { yprev[r] = 0.f; lsum[r] = 0.f; }
    __shared__ float lds_a[2][4][12];
    for (int d = 0; d < DD; ++d) {
        if (d >= 1) {
            #pragma unroll
            for (int n = 0; n < 2; ++n) {
                const float4 w0 = *reinterpret_cast<const float4*>(Wp0[n] + (d - 1) * HH + hb);
                const float w0a[4] = {w0.x, w0.y, w0.z, w0.w};
                #pragma unroll
                for (int s = 0; s < 4; ++s)
                    #pragma unroll
                    for (int r = 0; r < 4; ++r)
                        h0pre[n][s][r] = fmaf(yprev[r], w0a[s], h0pre[n][s][r]);
            }
            #pragma unroll
            for (int n = 0; n < 2; ++n)
                #pragma unroll
                for (int s = 0; s < 4; ++s)
                    if (deg[s] == d) {
                        const int k = (hb + s - (d - 1)) / 31;
                        #pragma unroll
                        for (int r = 0; r < 4; ++r)
                            lds_a[n][r][k] = fmaxf(h0pre[n][s][r], 0.f);
                    }
            __syncthreads();
            const bool nine = (d <= 8);
            #pragma unroll
            for (int n = 0; n < 2; ++n) {
                const float* W1r = Wp1[n] + (size_t)(d - 1) * HH + hb;
                float4 w1v[9];
                #pragma unroll
                for (int k = 0; k < 8; ++k)
                    w1v[k] = *reinterpret_cast<const float4*>(W1r + k * 31 * HH);
                if (nine) w1v[8] = *reinterpret_cast<const float4*>(W1r + 8 * 31 * HH);
                #pragma unroll
                for (int r = 0; r < 4; ++r) {
                    const float4 a03 = *reinterpret_cast<const float4*>(&lds_a[n][r][0]);
                    const float4 a47 = *reinterpret_cast<const float4*>(&lds_a[n][r][4]);
                    const float av[8] = {a03.x, a03.y, a03.z, a03.w, a47.x, a47.y, a47.z, a47.w};
                    #pragma unroll
                    for (int k = 0; k < 8; ++k) {
                        const float wk[4] = {w1v[k].x, w1v[k].y, w1v[k].z, w1v[k].w};
                        #pragma unroll
                        for (int s = 0; s < 4; ++s)
                            h1pre[n][s][r] = fmaf(av[k], wk[s], h1pre[n][s][r]);
                    }
                    if (nine) {
                        const float a8 = lds_a[n][r][8];
                        const float wk[4] = {w1v[8].x, w1v[8].y, w1v[8].z, w1v[8].w};
                        #pragma unroll
                        for (int s = 0; s < 4; ++s)
                            h1pre[n][s][r] = fmaf(a8, wk[s], h1pre[n][s][r]);
                    }
                }
            }
            #pragma unroll
            for (int n = 0; n < 2; ++n)
                #pragma unroll
                for (int s = 0; s < 4; ++s)
                    if (deg[s] == d)
                        #pragma unroll
                        for (int r = 0; r < 4; ++r)
                            r1[n][s][r] = fmaxf(h1pre[n][s][r], 0.f);
            __syncthreads();
        }
        float w2v[2][4];
        #pragma unroll
        for (int n = 0; n < 2; ++n)
            #pragma unroll
            for (int s = 0; s < 4; ++s)
                w2v[n][s] = Wp2[n][(hb + s) * DD + d];
        float red[2][4];
        #pragma unroll
        for (int n = 0; n < 2; ++n)
            #pragma unroll
            for (int r = 0; r < 4; ++r) {
                float p = 0.f;
                #pragma unroll
                for (int s = 0; s < 4; ++s) p = fmaf(r1[n][s][r], w2v[n][s], p);
                red[n][r] = p;
            }
        #pragma unroll
        for (int m = 1; m < 64; m <<= 1)
            #pragma unroll
            for (int n = 0; n < 2; ++n)
                #pragma unroll
                for (int r = 0; r < 4; ++r)
                    red[n][r] += __shfl_xor(red[n][r], m, 64);
        const float b2m = mub2[d], b2l = lvb2[d];
        #pragma unroll
        for (int r = 0; r < 4; ++r) {
            const float mu = red[0][r] + b2m;
            const float logstd = 0.5f * (red[1][r] + b2l);
            lsum[r] += logstd;
            const float yd = (x[(rowBase + r) * DD + d] - mu) / (__expf(logstd) + EPSF);
            yprev[r] = yd;
            if (lane == 0) out[(rowBase + r) * DD + d] = yd;
        }
    }
    if (lane == 0)
        #pragma unroll
        for (int r = 0; r < 4; ++r) out[BB * DD + rowBase + r] = lsum[r];
}

extern "C" void kernel_launch(void* const* d_in, const int* in_sizes, int n_in,
                              void* d_out, int out_size, void* d_ws, size_t ws_size,
                              hipStream_t stream) {
    const float* x    = (const float*)d_in[0];
    const float* muW0 = (const float*)d_in[1];
    const float* mub0 = (const float*)d_in[2];
    const float* muW1 = (const float*)d_in[3];
    const float* mub1 = (const float*)d_in[4];
    const float* muW2 = (const float*)d_in[5];
    const float* mub2 = (const float*)d_in[6];
    const float* lvW0 = (const float*)d_in[7];
    const float* lvb0 = (const float*)d_in[8];
    const float* lvW1 = (const float*)d_in[9];
    const float* lvb1 = (const float*)d_in[10];
    const float* lvW2 = (const float*)d_in[11];
    const float* lvb2 = (const float*)d_in[12];
    float* out = (float*)d_out;

    if (ws_size >= WSNEED) {
        float* ws = (float*)d_ws;
        made_prep<<<dim3(832), dim3(64), 0, stream>>>(
            muW0, mub0, muW1, mub1, muW2,
            lvW0, lvb0, lvW1, lvb1, lvW2, ws);
        made_main<<<dim3(BB / (4 * RR)), dim3(256), 0, stream>>>(ws, x, mub2, lvb2, out);
    } else {
        made_inv_fb<<<dim3(BB / 4), dim3(64), 0, stream>>>(x,
            muW0, mub0, muW1, mub1, muW2, mub2,
            lvW0, lvb0, lvW1, lvb1, lvW2, lvb2, out);
    }
}